// Round 6
// baseline (1697.906 us; speedup 1.0000x reference)
//
#include <hip/hip_runtime.h>
#include <hip/hip_bf16.h>
#include <stdint.h>

typedef float f32x4 __attribute__((ext_vector_type(4)));
typedef _Float16 half8 __attribute__((ext_vector_type(8)));
typedef _Float16 half2_ __attribute__((ext_vector_type(2)));

#define B_ 4096
#define T_ 256
#define D_ 18
#define H_ 32
#define GK 8192   // T_*H_
#define GN 512
#define KSPLIT 4
#define SLOT 520  // hist ring slot stride in halves (16*32 + 8 pad)

// ---------- helpers ----------
__device__ __forceinline__ float fsig(float x) {
  float e = __builtin_amdgcn_exp2f(-1.442695041f * x);
  return __builtin_amdgcn_rcpf(1.0f + e);
}
__device__ __forceinline__ float ftanh(float x) {
  float e = __builtin_amdgcn_exp2f(-2.885390082f * x);
  return 2.0f * __builtin_amdgcn_rcpf(1.0f + e) - 1.0f;
}
__device__ __forceinline__ half2_ pk16(float a, float b) {
  return __builtin_bit_cast(half2_, __builtin_amdgcn_cvt_pkrtz(a, b));
}
// Barrier draining ONLY LDS (lgkmcnt) — global loads/stores stay in flight.
__device__ __forceinline__ void ldsbar() {
  asm volatile("s_waitcnt lgkmcnt(0)\n\ts_barrier" ::: "memory");
}

// ---------- kernel 1: W1 fp32 -> fp16 (RNE) ----------
__global__ __launch_bounds__(256) void cvtw1_kernel(const float* __restrict__ w1,
                                                    unsigned short* __restrict__ dst) {
  int i = blockIdx.x * 256 + threadIdx.x;  // float4 index, total 1048576
  float4 v = ((const float4*)w1)[i];
  unsigned short a = __builtin_bit_cast(unsigned short, (_Float16)v.x);
  unsigned short b = __builtin_bit_cast(unsigned short, (_Float16)v.y);
  unsigned short c = __builtin_bit_cast(unsigned short, (_Float16)v.z);
  unsigned short d = __builtin_bit_cast(unsigned short, (_Float16)v.w);
  uint2 o; o.x = (unsigned)a | ((unsigned)b << 16); o.y = (unsigned)c | ((unsigned)d << 16);
  ((uint2*)dst)[i] = o;
}

// ---------- kernel 2: MFMA LSTM, LDS history ring + coalesced 8t flush ----------
// Block = 512 thr (8 waves) owns 16 batch elements. Wave w: tile-rows m =
// hl*4+gate, h_row = w*4+hl, orig W row = gate*32 + w*4 + hl. C layout
// row=lq*4+reg, col=lr: lane (lq,lr) gets (i,f,g,o) of h_row=w*4+lq, elem lr.
// h(t) written ONLY to LDS ring slot t&7 (swizzled 64B rows); every 8 t the
// ring is flushed to hs with coalesced 16B/lane stores (no per-t scatter).
__global__ __launch_bounds__(512) void lstm_kernel(
    const float* __restrict__ batch, const float* __restrict__ W_ih,
    const float* __restrict__ W_hh, const float* __restrict__ b_ih,
    const float* __restrict__ b_hh, _Float16* __restrict__ hs) {
  __shared__ _Float16 hist[8 * SLOT];

  const int tid = (int)threadIdx.x;
  const int lane = tid & 63;
  const int w = tid >> 6;
  const int lq = lane >> 4;
  const int lr = lane & 15;
  const int b0 = (int)blockIdx.x * 16;

  // constant A-fragments
  half8 wx, wh;
  {
    int grow = (lr & 3) * 32 + w * 4 + (lr >> 2);
#pragma unroll
    for (int j = 0; j < 8; ++j) {
      int k = lq * 8 + j;
      wx[j] = (k < D_) ? (_Float16)W_ih[grow * D_ + k] : (_Float16)0.0f;
      wh[j] = (_Float16)W_hh[grow * H_ + k];
    }
  }
  f32x4 bias4;
#pragma unroll
  for (int r = 0; r < 4; ++r) {
    int g = r * 32 + w * 4 + lq;
    bias4[r] = b_ih[g] + b_hh[g];
  }

  // zero the ring (h(0)=0 read comes from slot 7; zero all + pads)
  for (int i = tid; i < 8 * SLOT; i += 512) hist[i] = (_Float16)0.0f;

  // ring offsets (within-slot; slot base added as literal in unrolled steps)
  const int rdo = lr * 32 + ((lq ^ ((lr >> 1) & 3)) << 3);
  const int kcol = w * 4 + lq;
  const int wro = lr * 32 + ((((kcol >> 3) ^ ((lr >> 1) & 3))) << 3) + (kcol & 7);

  // flush mapping: thread -> (elem, slot, kgroup); reads b128 from ring,
  // writes 16B coalesced (512B contiguous per 32 lanes)
  const int fe = tid >> 5;
  const int fs = (tid >> 2) & 7;
  const int fg = tid & 3;
  const int fl_rd = fs * SLOT + fe * 32 + ((fg ^ ((fe >> 1) & 3)) << 3);
  _Float16* fl_wp = hs + (size_t)(b0 + fe) * GK + fs * H_ + fg * 8;

  // x prefetch: lane (lq,lr) needs x[b0+lr][t][lq*8..+7] (d<18)
  float4 nxt[4][2];
#pragma unroll
  for (int tt = 0; tt < 4; ++tt) {
    nxt[tt][0] = make_float4(0.f, 0.f, 0.f, 0.f);
    nxt[tt][1] = make_float4(0.f, 0.f, 0.f, 0.f);
  }
  const float* xbase = batch + (size_t)(b0 + lr) * T_ * D_ + lq * 8;

#define LOAD_CHUNK(tb)                                                         \
  do {                                                                         \
    if (lq < 2) {                                                              \
      const float* p_ = xbase + (tb) * D_;                                     \
      _Pragma("unroll") for (int tt = 0; tt < 4; ++tt) {                       \
        nxt[tt][0] = *(const float4*)p_;                                       \
        nxt[tt][1] = *(const float4*)(p_ + 4);                                 \
        p_ += D_;                                                              \
      }                                                                        \
    } else if (lq == 2) {                                                      \
      const float* p_ = xbase + (tb) * D_;                                     \
      _Pragma("unroll") for (int tt = 0; tt < 4; ++tt) {                       \
        nxt[tt][0].x = p_[0]; nxt[tt][0].y = p_[1];                            \
        p_ += D_;                                                              \
      }                                                                        \
    }                                                                          \
  } while (0)

#define CONV4                                                                  \
  do {                                                                         \
    _Pragma("unroll") for (int tt = 0; tt < 4; ++tt) {                         \
      union { half8 h8; half2_ h2[4]; } u;                                     \
      u.h2[0] = pk16(nxt[tt][0].x, nxt[tt][0].y);                              \
      u.h2[1] = pk16(nxt[tt][0].z, nxt[tt][0].w);                              \
      u.h2[2] = pk16(nxt[tt][1].x, nxt[tt][1].y);                              \
      u.h2[3] = pk16(nxt[tt][1].z, nxt[tt][1].w);                              \
      xf[tt] = u.h8;                                                           \
    }                                                                          \
  } while (0)

// step tt (0..7 within block): read h(t-1) from slot (tt+7)&7, write slot tt&7
#define STEP(tt)                                                               \
  do {                                                                         \
    half8 hf = *(const half8*)&hist[(((tt) + 7) & 7) * SLOT + rdo];            \
    f32x4 acc = bias4;                                                         \
    acc = __builtin_amdgcn_mfma_f32_16x16x32_f16(wx, xf[(tt) & 3], acc, 0, 0, 0); \
    acc = __builtin_amdgcn_mfma_f32_16x16x32_f16(wh, hf, acc, 0, 0, 0);        \
    float iv = fsig(acc[0]);                                                   \
    float fv = fsig(acc[1]);                                                   \
    float gv = ftanh(acc[2]);                                                  \
    float ov = fsig(acc[3]);                                                   \
    c = fmaf(fv, c, iv * gv);                                                  \
    float h = ov * ftanh(c);                                                   \
    hist[((tt) & 7) * SLOT + wro] = (_Float16)h;                               \
    ldsbar();                                                                  \
  } while (0)

  LOAD_CHUNK(0);
  ldsbar();  // zero-init visible

  float c = 0.0f;
  half8 xf[4];
  for (int blk = 0; blk < 32; ++blk) {
    const int base = blk * 8;
    CONV4;
    LOAD_CHUNK(base + 4);
    STEP(0); STEP(1); STEP(2); STEP(3);
    CONV4;
    if (blk < 31) LOAD_CHUNK(base + 8);
    STEP(4); STEP(5); STEP(6); STEP(7);
    // flush h(base..base+7): ring -> global, coalesced
    half8 hv = *(const half8*)&hist[fl_rd];
    *(half8*)(fl_wp + base * H_) = hv;
    ldsbar();  // flush reads done before next blk overwrites slot 0
  }
#undef STEP
#undef CONV4
#undef LOAD_CHUNK
}

// ---------- kernel 3: fp16 MFMA GEMM, BM=BN=128 BK=64, split-K=4 ----------
// Double-buffered LDS, 2-deep register prefetch, ONE lds-only barrier/iter:
// loads issued at iter i are consumed (ds_write) at i+2, ~2 full iterations
// (~800cy) later — covers L2/LLC latency without any vmcnt drain at barriers.
__global__ __launch_bounds__(256, 2) void gemm_kernel(
    const _Float16* __restrict__ Ahs, const _Float16* __restrict__ Bw1,
    float* __restrict__ part) {
  __shared__ _Float16 As[2 * 128 * 64];
  __shared__ _Float16 Bs[2 * 128 * 64];

  const int bid = (int)blockIdx.x;
  const int m0 = (bid & 31) << 7;
  const int n0 = ((bid >> 5) & 3) << 7;
  const int ksp = bid >> 7;
  const int k0 = ksp << 11;   // * 2048
  float* outp = part + (size_t)ksp * ((size_t)B_ * GN);

  const int tid = (int)threadIdx.x;
  const int lane = tid & 63, w = tid >> 6;
  const int wm = w & 1, wn = w >> 1;
  const int lq = lane >> 4, lr = lane & 15;

  // staging: LDS slot q of row holds global chunk q ^ (row&7)
  const _Float16* gA[4]; const _Float16* gB[4]; int lp[4];
#pragma unroll
  for (int j = 0; j < 4; ++j) {
    int p = tid + 256 * j;               // 0..1023
    int row = p >> 3, q = p & 7, cg = q ^ (row & 7);
    gA[j] = Ahs + (size_t)(m0 + row) * GK + k0 + cg * 8;
    gB[j] = Bw1 + (size_t)(n0 + row) * GK + k0 + cg * 8;
    lp[j] = p * 8;
  }

  int offA[4][2], offB[4][2];
#pragma unroll
  for (int mt = 0; mt < 4; ++mt)
#pragma unroll
    for (int ks = 0; ks < 2; ++ks) {
      int m = wm * 64 + mt * 16 + lr;
      offA[mt][ks] = m * 64 + (((lq + ks * 4) ^ (m & 7)) << 3);
      int n = wn * 64 + mt * 16 + lr;
      offB[mt][ks] = n * 64 + (((lq + ks * 4) ^ (n & 7)) << 3);
    }

  f32x4 acc[4][4];
#pragma unroll
  for (int mt = 0; mt < 4; ++mt)
#pragma unroll
    for (int nt = 0; nt < 4; ++nt) {
      acc[mt][nt][0] = 0.f; acc[mt][nt][1] = 0.f;
      acc[mt][nt][2] = 0.f; acc[mt][nt][3] = 0.f;
    }

  // preload iterations 0 and 1 into register sets 0/1
  half8 va[2][4], vb[2][4];
#pragma unroll
  for (int s = 0; s < 2; ++s)
#pragma unroll
    for (int j = 0; j < 4; ++j) {
      va[s][j] = *(const half8*)(gA[j] + s * 64);
      vb[s][j] = *(const half8*)(gB[j] + s * 64);
    }
#pragma unroll
  for (int j = 0; j < 4; ++j) { gA[j] += 128; gB[j] += 128; }

  for (int it = 0; it < 32; ++it) {
    const int p = it & 1;
    // commit set p to LDS buffer p (vmcnt wait: loads issued 2 iters ago)
#pragma unroll
    for (int j = 0; j < 4; ++j) {
      *(half8*)&As[p * 8192 + lp[j]] = va[p][j];
      *(half8*)&Bs[p * 8192 + lp[j]] = vb[p][j];
    }
    // refill set p with iter it+2 (stays in flight ~2 iterations)
    if (it < 30) {
#pragma unroll
      for (int j = 0; j < 4; ++j) {
        va[p][j] = *(const half8*)gA[j];
        vb[p][j] = *(const half8*)gB[j];
        gA[j] += 64; gB[j] += 64;
      }
    }
    ldsbar();  // buffer p writes visible; also fences reads of buffer p from it-2

    half8 af[4][2], bf[4][2];
#pragma unroll
    for (int mt = 0; mt < 4; ++mt)
#pragma unroll
      for (int ks = 0; ks < 2; ++ks) {
        af[mt][ks] = *(const half8*)&As[p * 8192 + offA[mt][ks]];
        bf[mt][ks] = *(const half8*)&Bs[p * 8192 + offB[mt][ks]];
      }
#pragma unroll
    for (int ks = 0; ks < 2; ++ks)
#pragma unroll
      for (int mt = 0; mt < 4; ++mt)
#pragma unroll
        for (int nt = 0; nt < 4; ++nt)
          acc[mt][nt] = __builtin_amdgcn_mfma_f32_16x16x32_f16(af[mt][ks], bf[nt][ks], acc[mt][nt], 0, 0, 0);
  }

  // epilogue: C layout col=lr, row=lq*4+reg; plain stores to this split's buffer
#pragma unroll
  for (int mt = 0; mt < 4; ++mt)
#pragma unroll
    for (int nt = 0; nt < 4; ++nt) {
      int n = n0 + wn * 64 + nt * 16 + lr;
#pragma unroll
      for (int r = 0; r < 4; ++r) {
        int m = m0 + wm * 64 + mt * 16 + lq * 4 + r;
        outp[(size_t)m * GN + n] = acc[mt][nt][r];
      }
    }
}

// ---------- kernel 4: head — sum KSPLIT partials, bias, relu, dot W2 ----------
__global__ __launch_bounds__(256) void head_kernel(const float* __restrict__ part,
                                                   const float* __restrict__ b1,
                                                   const float* __restrict__ W2,
                                                   const float* __restrict__ b2,
                                                   float* __restrict__ out) {
  const int b = (int)(blockIdx.x * 4 + (threadIdx.x >> 6));
  const int l = (int)(threadIdx.x & 63);
  const size_t stride = (size_t)B_ * GN;
  const float4* b14 = (const float4*)b1;
  const float4* w4 = (const float4*)W2;
  float s = 0.0f;
#pragma unroll
  for (int p = 0; p < 2; ++p) {
    int i = p * 64 + l;
    float4 hv = ((const float4*)(part + (size_t)b * GN))[i];
#pragma unroll
    for (int sp = 1; sp < KSPLIT; ++sp) {
      float4 pv = ((const float4*)(part + sp * stride + (size_t)b * GN))[i];
      hv.x += pv.x; hv.y += pv.y; hv.z += pv.z; hv.w += pv.w;
    }
    float4 bv = b14[i], wv = w4[i];
    float t0 = fmaxf(hv.x + bv.x, 0.0f);
    float t1 = fmaxf(hv.y + bv.y, 0.0f);
    float t2 = fmaxf(hv.z + bv.z, 0.0f);
    float t3 = fmaxf(hv.w + bv.w, 0.0f);
    s = fmaf(t0, wv.x, s); s = fmaf(t1, wv.y, s);
    s = fmaf(t2, wv.z, s); s = fmaf(t3, wv.w, s);
  }
#pragma unroll
  for (int off = 32; off >= 1; off >>= 1) s += __shfl_xor(s, off);
  if (l == 0) out[b] = s + b2[0];
}

extern "C" void kernel_launch(void* const* d_in, const int* in_sizes, int n_in,
                              void* d_out, int out_size, void* d_ws, size_t ws_size,
                              hipStream_t stream) {
  const float* batch = (const float*)d_in[0];
  const float* W_ih = (const float*)d_in[1];
  const float* W_hh = (const float*)d_in[2];
  const float* b_ih = (const float*)d_in[3];
  const float* b_hh = (const float*)d_in[4];
  const float* W1 = (const float*)d_in[5];
  const float* b1 = (const float*)d_in[6];
  const float* W2 = (const float*)d_in[7];
  const float* b2 = (const float*)d_in[8];
  float* out = (float*)d_out;

  char* ws = (char*)d_ws;
  _Float16* hs = (_Float16*)ws;                         // 4096*8192*2 = 67108864 B
  _Float16* w1h = (_Float16*)(ws + 67108864);           // 512*8192*2  =  8388608 B
  float* part = (float*)(ws + 67108864 + 8388608);      // 4*4096*512*4 = 33554432 B

  cvtw1_kernel<<<4096, 256, 0, stream>>>(W1, (unsigned short*)w1h);
  lstm_kernel<<<256, 512, 0, stream>>>(batch, W_ih, W_hh, b_ih, b_hh, hs);
  gemm_kernel<<<512, 256, 0, stream>>>(hs, w1h, part);
  head_kernel<<<1024, 256, 0, stream>>>(part, b1, W2, b2, out);
}

// Round 7
// 256.087 us; speedup vs baseline: 6.6302x; 6.6302x over previous
//
#include <hip/hip_runtime.h>
#include <hip/hip_bf16.h>
#include <stdint.h>

typedef float f32x4 __attribute__((ext_vector_type(4)));
typedef _Float16 half8 __attribute__((ext_vector_type(8)));
typedef _Float16 half2_ __attribute__((ext_vector_type(2)));

#define B_ 4096
#define T_ 256
#define D_ 18
#define H_ 32
#define GK 8192   // T_*H_
#define GN 512
#define KSPLIT 4
#define SLOT 520  // hist ring slot stride in halves (16*32 + 8 pad)

// ---------- helpers ----------
__device__ __forceinline__ float fsig(float x) {
  float e = __builtin_amdgcn_exp2f(-1.442695041f * x);
  return __builtin_amdgcn_rcpf(1.0f + e);
}
__device__ __forceinline__ float ftanh(float x) {
  float e = __builtin_amdgcn_exp2f(-2.885390082f * x);
  return 2.0f * __builtin_amdgcn_rcpf(1.0f + e) - 1.0f;
}
// Barrier draining ONLY LDS (lgkmcnt) — global loads/stores stay in flight.
__device__ __forceinline__ void ldsbar() {
  asm volatile("s_waitcnt lgkmcnt(0)\n\ts_barrier" ::: "memory");
}

// ---------- kernel 1: W1 fp32 -> fp16 (RNE) ----------
__global__ __launch_bounds__(256) void cvtw1_kernel(const float* __restrict__ w1,
                                                    unsigned short* __restrict__ dst) {
  int i = blockIdx.x * 256 + threadIdx.x;  // float4 index, total 1048576
  float4 v = ((const float4*)w1)[i];
  unsigned short a = __builtin_bit_cast(unsigned short, (_Float16)v.x);
  unsigned short b = __builtin_bit_cast(unsigned short, (_Float16)v.y);
  unsigned short c = __builtin_bit_cast(unsigned short, (_Float16)v.z);
  unsigned short d = __builtin_bit_cast(unsigned short, (_Float16)v.w);
  uint2 o; o.x = (unsigned)a | ((unsigned)b << 16); o.y = (unsigned)c | ((unsigned)d << 16);
  ((uint2*)dst)[i] = o;
}

// ---------- kernel 2: MFMA LSTM ----------
// Block = 512 thr (8 waves) owns 16 batch elems. Wave w: tile-rows m =
// hl*4+gate, h_row = w*4+hl, orig W row = gate*32 + w*4 + hl. C layout
// row=lq*4+reg, col=lr: lane (lq,lr) gets (i,f,g,o) of h_row=w*4+lq, elem lr.
// x: per-8t slab cooperatively loaded COALESCED (1 float4/thread) a full
// block ahead, converted fp16 into double-buffered LDS in B-frag layout —
// removes the 8x-redundant 64-lane-scatter loads that dominated R4-R6.
// h: LDS ring (slot t&7), coalesced global flush every 8 t.
__global__ __launch_bounds__(512) void lstm_kernel(
    const float* __restrict__ batch, const float* __restrict__ W_ih,
    const float* __restrict__ W_hh, const float* __restrict__ b_ih,
    const float* __restrict__ b_hh, _Float16* __restrict__ hs) {
  __shared__ _Float16 hist[8 * SLOT];
  __shared__ _Float16 xs[2 * 4096];  // [buf][t(8)][elem(16) x k(32)]

  const int tid = (int)threadIdx.x;
  const int lane = tid & 63;
  const int w = tid >> 6;
  const int lq = lane >> 4;
  const int lr = lane & 15;
  const int b0 = (int)blockIdx.x * 16;

  // constant A-fragments
  half8 wx, wh;
  {
    int grow = (lr & 3) * 32 + w * 4 + (lr >> 2);
#pragma unroll
    for (int j = 0; j < 8; ++j) {
      int k = lq * 8 + j;
      wx[j] = (k < D_) ? (_Float16)W_ih[grow * D_ + k] : (_Float16)0.0f;
      wh[j] = (_Float16)W_hh[grow * H_ + k];
    }
  }
  f32x4 bias4;
#pragma unroll
  for (int r = 0; r < 4; ++r) {
    int g = r * 32 + w * 4 + lq;
    bias4[r] = b_ih[g] + b_hh[g];
  }

  // fragment-read offset (row = elem, 32-half rows, chunk-swizzled)
  const int rdo = lr * 32 + ((lq ^ ((lr >> 1) & 3)) << 3);
  const int kcol = w * 4 + lq;
  const int wro = lr * 32 + ((((kcol >> 3) ^ ((lr >> 1) & 3))) << 3) + (kcol & 7);

  // flush mapping (ring -> hs, coalesced 16B/lane)
  const int fe = tid >> 5;
  const int fs = (tid >> 2) & 7;
  const int fg = tid & 3;
  const int fl_rd = fs * SLOT + fe * 32 + ((fg ^ ((fe >> 1) & 3)) << 3);
  _Float16* fl_wp = hs + (size_t)(b0 + fe) * GK + fs * H_ + fg * 8;

  // x slab staging: 576 float4 per 8t; thread -> (elem e, q-th float4 of 36)
  const int e0 = tid / 36, q0 = tid - e0 * 36;
  const int i1 = tid + 512;
  const int e1 = i1 / 36, q1 = i1 - e1 * 36;  // only tid<64
  const float* xld0 = batch + (size_t)(b0 + e0) * (T_ * D_) + q0 * 4;
  const float* xld1 = batch + (size_t)(b0 + e1) * (T_ * D_) + q1 * 4;
  float4 xv0, xv1;

#define XLOAD(tb)                                                              \
  do {                                                                         \
    xv0 = *(const float4*)(xld0 + (tb) * 144);                                 \
    if (tid < 64) xv1 = *(const float4*)(xld1 + (tb) * 144);                   \
  } while (0)

#define XPUT(E, Q, V, buf)                                                     \
  do {                                                                         \
    int swz_ = ((E) >> 1) & 3;                                                 \
    _Pragma("unroll") for (int j = 0; j < 4; ++j) {                            \
      int f_ = (Q) * 4 + j;                                                    \
      int to_ = (f_ * 57) >> 10; /* f/18 for f<1024 */                         \
      int d_ = f_ - to_ * 18;                                                  \
      float val_ = (j == 0) ? (V).x : (j == 1) ? (V).y : (j == 2) ? (V).z : (V).w; \
      xs[(buf) * 4096 + to_ * 512 + (E) * 32 + (((d_ >> 3) ^ swz_) << 3) + (d_ & 7)] = \
          (_Float16)val_;                                                      \
    }                                                                          \
  } while (0)

#define XSTORE(buf)                                                            \
  do {                                                                         \
    XPUT(e0, q0, xv0, buf);                                                    \
    if (tid < 64) XPUT(e1, q1, xv1, buf);                                      \
  } while (0)

// step tt (0..7): read h(t-1) from slot (tt+7)&7, x from xs slab; write slot tt
#define STEP(tt, xo)                                                           \
  do {                                                                         \
    half8 hf = *(const half8*)&hist[(((tt) + 7) & 7) * SLOT + rdo];            \
    half8 xf = *(const half8*)&xs[(xo) + (tt) * 512 + rdo];                    \
    f32x4 acc = bias4;                                                         \
    acc = __builtin_amdgcn_mfma_f32_16x16x32_f16(wx, xf, acc, 0, 0, 0);        \
    acc = __builtin_amdgcn_mfma_f32_16x16x32_f16(wh, hf, acc, 0, 0, 0);        \
    float iv = fsig(acc[0]);                                                   \
    float fv = fsig(acc[1]);                                                   \
    float gv = ftanh(acc[2]);                                                  \
    float ov = fsig(acc[3]);                                                   \
    c = fmaf(fv, c, iv * gv);                                                  \
    float h = ov * ftanh(c);                                                   \
    hist[((tt) & 7) * SLOT + wro] = (_Float16)h;                               \
    ldsbar();                                                                  \
  } while (0)

  XLOAD(0);  // loads fly while we zero LDS
  for (int i = tid; i < 8 * SLOT; i += 512) hist[i] = (_Float16)0.0f;
  for (int i = tid; i < 8192; i += 512) xs[i] = (_Float16)0.0f;
  ldsbar();
  XSTORE(0);   // one-time vmcnt wait
  XLOAD(1);
  ldsbar();

  float c = 0.0f;
  for (int blk = 0; blk < 32; ++blk) {
    const int xo = (blk & 1) * 4096;
    STEP(0, xo); STEP(1, xo); STEP(2, xo); STEP(3, xo);
    STEP(4, xo); STEP(5, xo); STEP(6, xo); STEP(7, xo);
    // flush h(blk*8 .. blk*8+7): ring -> global, coalesced (stays in flight)
    half8 hv = *(const half8*)&hist[fl_rd];
    *(half8*)(fl_wp + blk * 8 * H_) = hv;
    if (blk < 31) XSTORE((blk & 1) ^ 1);  // vmcnt: loads issued 8t ago — free
    if (blk < 30) XLOAD(blk + 2);
    ldsbar();
  }
#undef STEP
#undef XSTORE
#undef XPUT
#undef XLOAD
}

// ---------- kernel 3: fp16 MFMA GEMM, BM=BN=128 BK=64, split-K=4 ----------
// Double-buffered LDS, 2-deep register prefetch with COMPILE-TIME set/buffer
// parity (named sets va0/va1 — R6's va[p] dynamic index spilled to scratch).
__global__ __launch_bounds__(256, 2) void gemm_kernel(
    const _Float16* __restrict__ Ahs, const _Float16* __restrict__ Bw1,
    float* __restrict__ part) {
  __shared__ _Float16 As[2 * 128 * 64];
  __shared__ _Float16 Bs[2 * 128 * 64];

  const int bid = (int)blockIdx.x;
  const int m0 = (bid & 31) << 7;
  const int n0 = ((bid >> 5) & 3) << 7;
  const int ksp = bid >> 7;
  const int k0 = ksp << 11;   // * 2048
  float* outp = part + (size_t)ksp * ((size_t)B_ * GN);

  const int tid = (int)threadIdx.x;
  const int lane = tid & 63, w = tid >> 6;
  const int wm = w & 1, wn = w >> 1;
  const int lq = lane >> 4, lr = lane & 15;

  const _Float16* gA[4]; const _Float16* gB[4]; int lp[4];
#pragma unroll
  for (int j = 0; j < 4; ++j) {
    int p = tid + 256 * j;               // 0..1023
    int row = p >> 3, q = p & 7, cg = q ^ (row & 7);
    gA[j] = Ahs + (size_t)(m0 + row) * GK + k0 + cg * 8;
    gB[j] = Bw1 + (size_t)(n0 + row) * GK + k0 + cg * 8;
    lp[j] = p * 8;
  }

  int offA[4][2], offB[4][2];
#pragma unroll
  for (int mt = 0; mt < 4; ++mt)
#pragma unroll
    for (int ks = 0; ks < 2; ++ks) {
      int m = wm * 64 + mt * 16 + lr;
      offA[mt][ks] = m * 64 + (((lq + ks * 4) ^ (m & 7)) << 3);
      int n = wn * 64 + mt * 16 + lr;
      offB[mt][ks] = n * 64 + (((lq + ks * 4) ^ (n & 7)) << 3);
    }

  f32x4 acc[4][4];
#pragma unroll
  for (int mt = 0; mt < 4; ++mt)
#pragma unroll
    for (int nt = 0; nt < 4; ++nt) {
      acc[mt][nt][0] = 0.f; acc[mt][nt][1] = 0.f;
      acc[mt][nt][2] = 0.f; acc[mt][nt][3] = 0.f;
    }

  // preload k-chunks 0 (set0) and 1 (set1)
  half8 va0[4], vb0[4], va1[4], vb1[4];
#pragma unroll
  for (int j = 0; j < 4; ++j) {
    va0[j] = *(const half8*)gA[j];        vb0[j] = *(const half8*)gB[j];
    va1[j] = *(const half8*)(gA[j] + 64); vb1[j] = *(const half8*)(gB[j] + 64);
    gA[j] += 128; gB[j] += 128;
  }

#define GPHASE(SET, POFF, guard)                                               \
  do {                                                                         \
    _Pragma("unroll") for (int j = 0; j < 4; ++j) {                            \
      *(half8*)&As[(POFF) + lp[j]] = va##SET[j];                               \
      *(half8*)&Bs[(POFF) + lp[j]] = vb##SET[j];                               \
    }                                                                          \
    if (guard) {                                                               \
      _Pragma("unroll") for (int j = 0; j < 4; ++j) {                          \
        va##SET[j] = *(const half8*)gA[j];                                     \
        vb##SET[j] = *(const half8*)gB[j];                                     \
        gA[j] += 64; gB[j] += 64;                                              \
      }                                                                        \
    }                                                                          \
    ldsbar();                                                                  \
    half8 af[4][2], bf[4][2];                                                  \
    _Pragma("unroll") for (int mt = 0; mt < 4; ++mt)                           \
      _Pragma("unroll") for (int ks = 0; ks < 2; ++ks) {                       \
        af[mt][ks] = *(const half8*)&As[(POFF) + offA[mt][ks]];                \
        bf[mt][ks] = *(const half8*)&Bs[(POFF) + offB[mt][ks]];                \
      }                                                                        \
    _Pragma("unroll") for (int ks = 0; ks < 2; ++ks)                           \
      _Pragma("unroll") for (int mt = 0; mt < 4; ++mt)                         \
        _Pragma("unroll") for (int nt = 0; nt < 4; ++nt)                       \
          acc[mt][nt] = __builtin_amdgcn_mfma_f32_16x16x32_f16(                \
              af[mt][ks], bf[nt][ks], acc[mt][nt], 0, 0, 0);                   \
  } while (0)

  for (int it2 = 0; it2 < 16; ++it2) {
    const bool g = (it2 < 15);
    GPHASE(0, 0, g);
    GPHASE(1, 8192, g);
  }
#undef GPHASE

  // epilogue: C layout col=lr, row=lq*4+reg; plain stores to this split's buffer
#pragma unroll
  for (int mt = 0; mt < 4; ++mt)
#pragma unroll
    for (int nt = 0; nt < 4; ++nt) {
      int n = n0 + wn * 64 + nt * 16 + lr;
#pragma unroll
      for (int r = 0; r < 4; ++r) {
        int m = m0 + wm * 64 + mt * 16 + lq * 4 + r;
        outp[(size_t)m * GN + n] = acc[mt][nt][r];
      }
    }
}

// ---------- kernel 4: head — sum KSPLIT partials, bias, relu, dot W2 ----------
__global__ __launch_bounds__(256) void head_kernel(const float* __restrict__ part,
                                                   const float* __restrict__ b1,
                                                   const float* __restrict__ W2,
                                                   const float* __restrict__ b2,
                                                   float* __restrict__ out) {
  const int b = (int)(blockIdx.x * 4 + (threadIdx.x >> 6));
  const int l = (int)(threadIdx.x & 63);
  const size_t stride = (size_t)B_ * GN;
  const float4* b14 = (const float4*)b1;
  const float4* w4 = (const float4*)W2;
  float s = 0.0f;
#pragma unroll
  for (int p = 0; p < 2; ++p) {
    int i = p * 64 + l;
    float4 hv = ((const float4*)(part + (size_t)b * GN))[i];
#pragma unroll
    for (int sp = 1; sp < KSPLIT; ++sp) {
      float4 pv = ((const float4*)(part + sp * stride + (size_t)b * GN))[i];
      hv.x += pv.x; hv.y += pv.y; hv.z += pv.z; hv.w += pv.w;
    }
    float4 bv = b14[i], wv = w4[i];
    float t0 = fmaxf(hv.x + bv.x, 0.0f);
    float t1 = fmaxf(hv.y + bv.y, 0.0f);
    float t2 = fmaxf(hv.z + bv.z, 0.0f);
    float t3 = fmaxf(hv.w + bv.w, 0.0f);
    s = fmaf(t0, wv.x, s); s = fmaf(t1, wv.y, s);
    s = fmaf(t2, wv.z, s); s = fmaf(t3, wv.w, s);
  }
#pragma unroll
  for (int off = 32; off >= 1; off >>= 1) s += __shfl_xor(s, off);
  if (l == 0) out[b] = s + b2[0];
}

extern "C" void kernel_launch(void* const* d_in, const int* in_sizes, int n_in,
                              void* d_out, int out_size, void* d_ws, size_t ws_size,
                              hipStream_t stream) {
  const float* batch = (const float*)d_in[0];
  const float* W_ih = (const float*)d_in[1];
  const float* W_hh = (const float*)d_in[2];
  const float* b_ih = (const float*)d_in[3];
  const float* b_hh = (const float*)d_in[4];
  const float* W1 = (const float*)d_in[5];
  const float* b1 = (const float*)d_in[6];
  const float* W2 = (const float*)d_in[7];
  const float* b2 = (const float*)d_in[8];
  float* out = (float*)d_out;

  char* ws = (char*)d_ws;
  _Float16* hs = (_Float16*)ws;                         // 4096*8192*2 = 67108864 B
  _Float16* w1h = (_Float16*)(ws + 67108864);           // 512*8192*2  =  8388608 B
  float* part = (float*)(ws + 67108864 + 8388608);      // 4*4096*512*4 = 33554432 B

  cvtw1_kernel<<<4096, 256, 0, stream>>>(W1, (unsigned short*)w1h);
  lstm_kernel<<<256, 512, 0, stream>>>(batch, W_ih, W_hh, b_ih, b_hh, hs);
  gemm_kernel<<<512, 256, 0, stream>>>(hs, w1h, part);
  head_kernel<<<1024, 256, 0, stream>>>(part, b1, W2, b2, out);
}